// Round 3
// baseline (123.627 us; speedup 1.0000x reference)
//
#include <hip/hip_runtime.h>
#include <hip/hip_bf16.h>

#define NCH 64
#define NEL 10
// Basis: 172 cubic chunks (72 full-pair j<=7, 100 h1-only j>=8) + 20 tail chunks = 192 chunks
// = 48 MFMA K-steps of 32. Table layout: W[ec][o][chunk n=KK*4+g][8 j] bf16.
#define NCHUNK 192
#define NSTEP 48

#define WS_OFFS  0
#define WS_LIST  1024
#define WS_W     8192        // 640 * 16 * 192 * 8 * 2B = 31.46 MB

typedef __attribute__((ext_vector_type(8))) short  short8v;
typedef __attribute__((ext_vector_type(4))) float  float4v;
typedef __attribute__((ext_vector_type(4))) int    int4v;

// pair enumerations (must match k_build's runtime decode):
// full region (j<=7): for j in 0..7: for i in 0..j   (36 pairs)
__host__ __device__ constexpr int PJF(int p) { int j = 0; while (p >= j + 1) { p -= j + 1; ++j; } return j; }
__host__ __device__ constexpr int PIF(int p) { int j = 0; while (p >= j + 1) { p -= j + 1; ++j; } return p; }
// h1 region (j>=8): for j in 8..15: for i in 0..j    (100 pairs)
__host__ __device__ constexpr int PJH(int p) { int j = 8; while (p >= j + 1) { p -= j + 1; ++j; } return j; }
__host__ __device__ constexpr int PIH(int p) { int j = 8; while (p >= j + 1) { p -= j + 1; ++j; } return p; }

__device__ __forceinline__ unsigned short f_to_bf16u(float f) {
  union { float f; unsigned int i; } v; v.f = f;
  unsigned int x = v.i;
  unsigned int r = (x + 0x7fffu + ((x >> 16) & 1u)) >> 16;
  return (unsigned short)r;
}

// ---------------- kernel 0: bucket nodes by element ----------------
__global__ void k_lists(const int* __restrict__ idx, int* __restrict__ ws_offs,
                        int* __restrict__ ws_list) {
  __shared__ int cnt[NEL];
  __shared__ int base[NEL + 1];
  int t = threadIdx.x;
  if (t < NEL) cnt[t] = 0;
  __syncthreads();
  int e = idx[t];
  int pos = atomicAdd(&cnt[e], 1);
  __syncthreads();
  if (t == 0) {
    int a = 0;
    for (int i = 0; i < NEL; ++i) { base[i] = a; a += cnt[i]; }
    base[NEL] = a;
  }
  __syncthreads();
  ws_list[base[e] + pos] = t;
  if (t <= NEL) ws_offs[t] = base[t];
}

// ---------------- kernel 1: build W[ec][o][chunk][8] (bf16) ----------------
// grid = (o*10+e)*8 + (c&7)  -> blk%8 == c&7 == ec&7 matches k_main's XCD home.
// 192 threads, thread = chunk n. Loops 8 channels c = (c&7) + 8*m.
__global__ __launch_bounds__(192) void k_build(const float* __restrict__ U3,
                                               const float* __restrict__ U2,
                                               const float* __restrict__ U1,
                                               const float* __restrict__ w3,
                                               const float* __restrict__ w2,
                                               const float* __restrict__ w1,
                                               unsigned short* __restrict__ W) {
  int blk = blockIdx.x;
  int x7 = blk & 7;
  int oe = blk >> 3;
  int e = oe % 10;
  int o = oe / 10;
  int n = threadIdx.x;                 // chunk id 0..191

  int ci = 0, cj = 0, h = 1, type;     // type 0 = cubic, 1 = tail
  int r0 = 0;
  if (n < 72) {                        // full-pair region
    int p = n >> 1; h = n & 1;
    int j = 0; while (p >= j + 1) { p -= j + 1; ++j; }
    ci = p; cj = j; type = 0;
  } else if (n < 172) {                // h1 region
    int p = n - 72; h = 1;
    int j = 8; while (p >= j + 1) { p -= j + 1; ++j; }
    ci = p; cj = j; type = 0;
  } else {
    r0 = (n - 172) * 8; type = 1;
  }
  int ta[8], tb[8];
  if (type == 1) {
#pragma unroll
    for (int jj = 0; jj < 8; ++jj) {
      int r = r0 + jj;
      if (r < 136) {                   // quad pairs, i-major (matches k_main sT)
        int p = r, i2 = 0; while (p >= 16 - i2) { p -= 16 - i2; ++i2; }
        ta[jj] = i2; tb[jj] = i2 + p;
      } else if (r < 152) { ta[jj] = r - 136; tb[jj] = -1; }
      else { ta[jj] = -2; tb[jj] = -2; }
    }
  }

  for (int m = 0; m < 8; ++m) {
    int c = x7 + 8 * m;
    int ec = e * 64 + c;
    float val[8];
    if (type == 0) {
      float wv[16];
#pragma unroll
      for (int k = 0; k < 16; ++k) wv[k] = w3[(e * 16 + k) * NCH + c];
#pragma unroll
      for (int jj = 0; jj < 8; ++jj) {
        int l = h * 8 + jj;
        float s = 0.f;
        if (l >= cj) {                 // canonical i<=j<=l
          const float* line = U3 + ((((size_t)o * 16 + ci) * 16 + cj) * 16 + l) * 16;
#pragma unroll
          for (int k = 0; k < 16; ++k) s += line[k] * wv[k];
          float mult = (ci == cj) ? (cj == l ? 1.f : 3.f) : (cj == l ? 3.f : 6.f);
          s *= mult;
        }
        val[jj] = s;
      }
    } else {
      float w2v[8], w1v[4];
#pragma unroll
      for (int k = 0; k < 8; ++k) w2v[k] = w2[(e * 8 + k) * NCH + c];
#pragma unroll
      for (int k = 0; k < 4; ++k) w1v[k] = w1[(e * 4 + k) * NCH + c];
#pragma unroll
      for (int jj = 0; jj < 8; ++jj) {
        float s = 0.f;
        int a = ta[jj];
        if (a >= 0 && tb[jj] >= 0) {   // quad: (2-delta) * sum_k U2 w2
          const float* line = U2 + (((o * 16 + a) * 16) + tb[jj]) * 8;
#pragma unroll
          for (int k = 0; k < 8; ++k) s += line[k] * w2v[k];
          if (a != tb[jj]) s *= 2.f;
        } else if (a >= 0) {           // linear
          const float* line = U1 + (o * 16 + a) * 4;
#pragma unroll
          for (int k = 0; k < 4; ++k) s += line[k] * w1v[k];
        }
        val[jj] = s;
      }
    }
    uint4 st;
    st.x = (unsigned)f_to_bf16u(val[0]) | ((unsigned)f_to_bf16u(val[1]) << 16);
    st.y = (unsigned)f_to_bf16u(val[2]) | ((unsigned)f_to_bf16u(val[3]) << 16);
    st.z = (unsigned)f_to_bf16u(val[4]) | ((unsigned)f_to_bf16u(val[5]) << 16);
    st.w = (unsigned)f_to_bf16u(val[6]) | ((unsigned)f_to_bf16u(val[7]) << 16);
    *(uint4*)(W + (((size_t)ec * 16 + o) * NCHUNK + n) * 8) = st;   // wave-contiguous 1KB
  }
}

// ---------------- kernel 2: MFMA main ----------------
#define PACK_MFMA(M0, M1, M2, M3, M4, M5, M6, M7, KK, ACC) { \
  int b0, b1, b2, b3; \
  asm("v_cvt_pk_bf16_f32 %0, %1, %2" : "=v"(b0) : "v"(M0), "v"(M1)); \
  asm("v_cvt_pk_bf16_f32 %0, %1, %2" : "=v"(b1) : "v"(M2), "v"(M3)); \
  asm("v_cvt_pk_bf16_f32 %0, %1, %2" : "=v"(b2) : "v"(M4), "v"(M5)); \
  asm("v_cvt_pk_bf16_f32 %0, %1, %2" : "=v"(b3) : "v"(M6), "v"(M7)); \
  int4v ai = {b0, b1, b2, b3}; \
  short8v av = __builtin_bit_cast(short8v, ai); \
  short8v bv = *(const short8v*)(bp + (KK) * 32); \
  ACC = __builtin_amdgcn_mfma_f32_16x16x32_bf16(av, bv, ACC, 0, 0, 0); \
}

#define FULL_STEP(KK, ACC) { \
  constexpr int iA = PIF(2 * (KK)), jA = PJF(2 * (KK)); \
  constexpr int iB = PIF(2 * (KK) + 1), jB = PJF(2 * (KK) + 1); \
  float xxA = xr[iA] * xr[jA]; \
  float xxB = xr[iB] * xr[jB]; \
  float xx = selOdd ? xxB : xxA; \
  PACK_MFMA(xx * xsF[0], xx * xsF[1], xx * xsF[2], xx * xsF[3], \
            xx * xsF[4], xx * xsF[5], xx * xsF[6], xx * xsF[7], KK, ACC) \
}

#define H1_STEP(KK, ACC) { \
  constexpr int q = 4 * ((KK) - 18); \
  constexpr int i0 = PIH(q), j0 = PJH(q); \
  constexpr int i1 = PIH(q + 1), j1 = PJH(q + 1); \
  constexpr int i2 = PIH(q + 2), j2 = PJH(q + 2); \
  constexpr int i3 = PIH(q + 3), j3 = PJH(q + 3); \
  float xx0 = xr[i0] * xr[j0], xx1 = xr[i1] * xr[j1]; \
  float xx2 = xr[i2] * xr[j2], xx3 = xr[i3] * xr[j3]; \
  float xxE = selG1 ? xx1 : xx0; \
  float xxO = selG1 ? xx3 : xx2; \
  float xx = selOdd ? xxO : xxE; \
  PACK_MFMA(xx * xr[8], xx * xr[9], xx * xr[10], xx * xr[11], \
            xx * xr[12], xx * xr[13], xx * xr[14], xx * xr[15], KK, ACC) \
}

#define TAIL_STEP(KK, ACC) { \
  float mv[8]; \
  _Pragma("unroll") \
  for (int jj = 0; jj < 8; ++jj) { \
    int spec = sTw[((KK) - 43) * 32 + g * 8 + jj]; \
    mv[jj] = sXw[spec & 31] * sXw[(spec >> 8) & 31]; \
  } \
  PACK_MFMA(mv[0], mv[1], mv[2], mv[3], mv[4], mv[5], mv[6], mv[7], KK, ACC) \
}

__global__ __launch_bounds__(256, 4) void k_main(const float* __restrict__ x,
                                                 const int* __restrict__ offs,
                                                 const int* __restrict__ list,
                                                 const unsigned short* __restrict__ W,
                                                 float* __restrict__ out) {
  __shared__ float sX[4][16][18];
  __shared__ int sT[4][160];
  int t = threadIdx.x;
  int w = t >> 6, lane = t & 63;
  int rc = lane & 15;
  int g = lane >> 4;
  bool selOdd = g >= 2;
  bool selG1 = g & 1;

  int u = blockIdx.x;
  int ec = (u >> 4) * 8 + (u & 7);     // blocks u and u+8 share ec, same XCD (u%8)
  int half = (u >> 3) & 1;
  int e = ec >> 6, c = ec & 63;

  float* sXw = &sX[w][rc][0];
  int* sTw = &sT[w][0];
  for (int r = lane; r < 160; r += 64) {   // per-wave spec fill: no barrier needed
    int a, b;
    if (r < 136) { int p = r, i2 = 0; while (p >= 16 - i2) { p -= 16 - i2; ++i2; } a = i2; b = i2 + p; }
    else if (r < 152) { a = r - 136; b = 16; }
    else { a = 17; b = 17; }
    sTw[r] = a | (b << 8);
  }

  int off = offs[e], nb = offs[e + 1] - off;
  int nt = (nb + 15) >> 4;
  const unsigned short* bp = W + (((size_t)ec * 16 + rc) * NCHUNK + g) * 8;

  for (int tile = half * 4 + w; tile < nt; tile += 8) {
    int m = tile * 16 + rc;
    int node = list[off + (m < nb ? m : nb - 1)];
    float xr[16];
    {
      const float4* xp = (const float4*)(x + ((size_t)node * NCH + c) * 16);
      float4 q0 = xp[0], q1 = xp[1], q2 = xp[2], q3 = xp[3];
      xr[0] = q0.x; xr[1] = q0.y; xr[2] = q0.z; xr[3] = q0.w;
      xr[4] = q1.x; xr[5] = q1.y; xr[6] = q1.z; xr[7] = q1.w;
      xr[8] = q2.x; xr[9] = q2.y; xr[10] = q2.z; xr[11] = q2.w;
      xr[12] = q3.x; xr[13] = q3.y; xr[14] = q3.z; xr[15] = q3.w;
    }
    float xsF[8];
#pragma unroll
    for (int j = 0; j < 8; ++j) xsF[j] = selG1 ? xr[8 + j] : xr[j];
    if (g == 0) {                      // publish row for tail steps (same-wave use only)
#pragma unroll
      for (int l = 0; l < 16; ++l) sXw[l] = xr[l];
      sXw[16] = 1.f; sXw[17] = 0.f;
    }

    float4v acc0 = {0.f, 0.f, 0.f, 0.f};
    float4v acc1 = {0.f, 0.f, 0.f, 0.f};
#define S2F(K) FULL_STEP(K, acc0) FULL_STEP((K) + 1, acc1)
#define S2H(K) H1_STEP(K, acc0) H1_STEP((K) + 1, acc1)
    S2F(0) S2F(2) S2F(4) S2F(6) S2F(8) S2F(10) S2F(12) S2F(14) S2F(16)
    S2H(18) S2H(20) S2H(22) S2H(24) S2H(26) S2H(28) S2H(30) S2H(32)
    S2H(34) S2H(36) S2H(38) S2H(40)
    H1_STEP(42, acc0)
    TAIL_STEP(43, acc1)
    TAIL_STEP(44, acc0) TAIL_STEP(45, acc1)
    TAIL_STEP(46, acc0) TAIL_STEP(47, acc1)
    float4v accs = acc0 + acc1;

#pragma unroll
    for (int r2 = 0; r2 < 4; ++r2) {
      int row = g * 4 + r2;
      int mrow = tile * 16 + row;
      if (mrow < nb) {
        int nd = __shfl(node, row);
        out[((size_t)nd * NCH + c) * 16 + rc] = accs[r2];
      }
    }
  }
}

extern "C" void kernel_launch(void* const* d_in, const int* in_sizes, int n_in,
                              void* d_out, int out_size, void* d_ws, size_t ws_size,
                              hipStream_t stream) {
  (void)in_sizes; (void)n_in; (void)out_size; (void)ws_size;
  const float* x   = (const float*)d_in[0];
  const int*   idx = (const int*)d_in[1];
  const float* w1  = (const float*)d_in[2];
  const float* w2  = (const float*)d_in[3];
  const float* w3  = (const float*)d_in[4];
  const float* U1  = (const float*)d_in[5];
  const float* U2  = (const float*)d_in[6];
  const float* U3  = (const float*)d_in[7];
  float* out = (float*)d_out;
  char* ws = (char*)d_ws;
  int* ws_offs = (int*)(ws + WS_OFFS);
  int* ws_list = (int*)(ws + WS_LIST);
  unsigned short* W = (unsigned short*)(ws + WS_W);

  hipLaunchKernelGGL(k_lists, dim3(1), dim3(1024), 0, stream, idx, ws_offs, ws_list);
  hipLaunchKernelGGL(k_build, dim3(1280), dim3(192), 0, stream, U3, U2, U1, w3, w2, w1, W);
  hipLaunchKernelGGL(k_main, dim3(1280), dim3(256), 0, stream, x, ws_offs, ws_list, W, out);
}

// Round 4
// 72.180 us; speedup vs baseline: 1.7127x; 1.7127x over previous
//
#include <hip/hip_runtime.h>
#include <hip/hip_bf16.h>

#define NCH 64
#define NEL 10
// Basis: 172 cubic chunks (72 full-pair j<=7, 100 h1-only j>=8) + 20 tail chunks = 192 chunks
// = 48 MFMA K-steps of 32. Table layout: W[ec][o][chunk n=KK*4+g][8 j] bf16.
#define NCHUNK 192
#define NSTEP 48

#define WS_OFFS  0
#define WS_LIST  1024
#define WS_W     8192        // 640 * 16 * 192 * 8 * 2B = 31.46 MB

typedef __attribute__((ext_vector_type(8))) short  short8v;
typedef __attribute__((ext_vector_type(4))) float  float4v;
typedef __attribute__((ext_vector_type(4))) int    int4v;

// pair enumerations (must match k_build's runtime decode):
// full region (j<=7): for j in 0..7: for i in 0..j   (36 pairs)
__host__ __device__ constexpr int PJF(int p) { int j = 0; while (p >= j + 1) { p -= j + 1; ++j; } return j; }
__host__ __device__ constexpr int PIF(int p) { int j = 0; while (p >= j + 1) { p -= j + 1; ++j; } return p; }
// h1 region (j>=8): for j in 8..15: for i in 0..j    (100 pairs)
__host__ __device__ constexpr int PJH(int p) { int j = 8; while (p >= j + 1) { p -= j + 1; ++j; } return j; }
__host__ __device__ constexpr int PIH(int p) { int j = 8; while (p >= j + 1) { p -= j + 1; ++j; } return p; }

__device__ __forceinline__ unsigned short f_to_bf16u(float f) {
  union { float f; unsigned int i; } v; v.f = f;
  unsigned int x = v.i;
  unsigned int r = (x + 0x7fffu + ((x >> 16) & 1u)) >> 16;
  return (unsigned short)r;
}

// ---------------- kernel 0: bucket nodes by element ----------------
__global__ void k_lists(const int* __restrict__ idx, int* __restrict__ ws_offs,
                        int* __restrict__ ws_list) {
  __shared__ int cnt[NEL];
  __shared__ int base[NEL + 1];
  int t = threadIdx.x;
  if (t < NEL) cnt[t] = 0;
  __syncthreads();
  int e = idx[t];
  int pos = atomicAdd(&cnt[e], 1);
  __syncthreads();
  if (t == 0) {
    int a = 0;
    for (int i = 0; i < NEL; ++i) { base[i] = a; a += cnt[i]; }
    base[NEL] = a;
  }
  __syncthreads();
  ws_list[base[e] + pos] = t;
  if (t <= NEL) ws_offs[t] = base[t];
}

// ---------------- kernel 1: build W[ec][o][chunk][8] (bf16) ----------------
// grid = (o*10+e)*8 + (c&7). 192 threads, thread = chunk n.
// v2: U3 lines loaded ONCE per thread as dwordx4 (hoisted out of the channel
// loop); w3/w2/w1 8-channel slices staged in LDS (block-uniform broadcast).
__global__ __launch_bounds__(192) void k_build(const float* __restrict__ U3,
                                               const float* __restrict__ U2,
                                               const float* __restrict__ U1,
                                               const float* __restrict__ w3,
                                               const float* __restrict__ w2,
                                               const float* __restrict__ w1,
                                               unsigned short* __restrict__ W) {
  int blk = blockIdx.x;
  int x7 = blk & 7;
  int oe = blk >> 3;
  int e = oe % 10;
  int o = oe / 10;
  int n = threadIdx.x;                 // chunk id 0..191

  __shared__ float sw3[16 * 8];        // [k][m], c = x7 + 8*m
  __shared__ float sw2[8 * 8];
  __shared__ float sw1[4 * 8];
  if (n < 128) { int k = n >> 3, m = n & 7; sw3[n] = w3[(e * 16 + k) * NCH + x7 + 8 * m]; }
  else { int q = n - 128; if (q < 64) { int k = q >> 3, m = q & 7; sw2[q] = w2[(e * 8 + k) * NCH + x7 + 8 * m]; } }
  if (n < 32) { int k = n >> 3, m = n & 7; sw1[n] = w1[(e * 4 + k) * NCH + x7 + 8 * m]; }
  __syncthreads();

  int ci = 0, cj = 0, h = 1, type;     // type 0 = cubic, 1 = tail
  int r0 = 0;
  if (n < 72) {                        // full-pair region
    int p = n >> 1; h = n & 1;
    int j = 0; while (p >= j + 1) { p -= j + 1; ++j; }
    ci = p; cj = j; type = 0;
  } else if (n < 172) {                // h1 region
    int p = n - 72; h = 1;
    int j = 8; while (p >= j + 1) { p -= j + 1; ++j; }
    ci = p; cj = j; type = 0;
  } else {
    r0 = (n - 172) * 8; type = 1;
  }

  float acc[8][8];                     // [m][jj] — all static indexing
#pragma unroll
  for (int m = 0; m < 8; ++m)
#pragma unroll
    for (int jj = 0; jj < 8; ++jj) acc[m][jj] = 0.f;

  if (type == 0) {
#pragma unroll
    for (int jj = 0; jj < 8; ++jj) {
      int l = h * 8 + jj;
      if (l >= cj) {                   // canonical i<=j<=l
        const float4* lp = (const float4*)(U3 + ((((size_t)o * 16 + ci) * 16 + cj) * 16 + l) * 16);
        float4 q0 = lp[0], q1 = lp[1], q2 = lp[2], q3 = lp[3];
        float line[16] = {q0.x, q0.y, q0.z, q0.w, q1.x, q1.y, q1.z, q1.w,
                          q2.x, q2.y, q2.z, q2.w, q3.x, q3.y, q3.z, q3.w};
        float mult = (ci == cj) ? (cj == l ? 1.f : 3.f) : (cj == l ? 3.f : 6.f);
#pragma unroll
        for (int m = 0; m < 8; ++m) {
          float s = 0.f;
#pragma unroll
          for (int k = 0; k < 16; ++k) s += line[k] * sw3[k * 8 + m];
          acc[m][jj] = s * mult;
        }
      }
    }
  } else {
#pragma unroll
    for (int jj = 0; jj < 8; ++jj) {
      int r = r0 + jj;
      if (r < 136) {                   // quad pairs, i-major (matches k_main sT)
        int p = r, i2 = 0; while (p >= 16 - i2) { p -= 16 - i2; ++i2; }
        int a = i2, b = i2 + p;
        const float4* lp = (const float4*)(U2 + (((o * 16 + a) * 16) + b) * 8);
        float4 q0 = lp[0], q1 = lp[1];
        float line[8] = {q0.x, q0.y, q0.z, q0.w, q1.x, q1.y, q1.z, q1.w};
        float sc = (a == b) ? 1.f : 2.f;
#pragma unroll
        for (int m = 0; m < 8; ++m) {
          float s = 0.f;
#pragma unroll
          for (int k = 0; k < 8; ++k) s += line[k] * sw2[k * 8 + m];
          acc[m][jj] = s * sc;
        }
      } else if (r < 152) {            // linear
        int a = r - 136;
        const float4* lp = (const float4*)(U1 + (o * 16 + a) * 4);
        float4 q0 = lp[0];
        float line[4] = {q0.x, q0.y, q0.z, q0.w};
#pragma unroll
        for (int m = 0; m < 8; ++m) {
          float s = 0.f;
#pragma unroll
          for (int k = 0; k < 4; ++k) s += line[k] * sw1[k * 8 + m];
          acc[m][jj] = s;
        }
      }
    }
  }

#pragma unroll
  for (int m = 0; m < 8; ++m) {
    int c = x7 + 8 * m;
    int ec = e * 64 + c;
    uint4 st;
    st.x = (unsigned)f_to_bf16u(acc[m][0]) | ((unsigned)f_to_bf16u(acc[m][1]) << 16);
    st.y = (unsigned)f_to_bf16u(acc[m][2]) | ((unsigned)f_to_bf16u(acc[m][3]) << 16);
    st.z = (unsigned)f_to_bf16u(acc[m][4]) | ((unsigned)f_to_bf16u(acc[m][5]) << 16);
    st.w = (unsigned)f_to_bf16u(acc[m][6]) | ((unsigned)f_to_bf16u(acc[m][7]) << 16);
    *(uint4*)(W + (((size_t)ec * 16 + o) * NCHUNK + n) * 8) = st;   // wave-contiguous 1KB
  }
}

// ---------------- kernel 2: MFMA main ----------------
#define PACK_MFMA(M0, M1, M2, M3, M4, M5, M6, M7, KK, ACC) { \
  int b0, b1, b2, b3; \
  asm("v_cvt_pk_bf16_f32 %0, %1, %2" : "=v"(b0) : "v"(M0), "v"(M1)); \
  asm("v_cvt_pk_bf16_f32 %0, %1, %2" : "=v"(b1) : "v"(M2), "v"(M3)); \
  asm("v_cvt_pk_bf16_f32 %0, %1, %2" : "=v"(b2) : "v"(M4), "v"(M5)); \
  asm("v_cvt_pk_bf16_f32 %0, %1, %2" : "=v"(b3) : "v"(M6), "v"(M7)); \
  int4v ai = {b0, b1, b2, b3}; \
  short8v av = __builtin_bit_cast(short8v, ai); \
  short8v bv = *(const short8v*)(bp + (KK) * 32); \
  ACC = __builtin_amdgcn_mfma_f32_16x16x32_bf16(av, bv, ACC, 0, 0, 0); \
}

#define FULL_STEP(KK, ACC) { \
  constexpr int iA = PIF(2 * (KK)), jA = PJF(2 * (KK)); \
  constexpr int iB = PIF(2 * (KK) + 1), jB = PJF(2 * (KK) + 1); \
  float xxA = xr[iA] * xr[jA]; \
  float xxB = xr[iB] * xr[jB]; \
  float xx = selOdd ? xxB : xxA; \
  PACK_MFMA(xx * xsF[0], xx * xsF[1], xx * xsF[2], xx * xsF[3], \
            xx * xsF[4], xx * xsF[5], xx * xsF[6], xx * xsF[7], KK, ACC) \
}

#define H1_STEP(KK, ACC) { \
  constexpr int q = 4 * ((KK) - 18); \
  constexpr int i0 = PIH(q), j0 = PJH(q); \
  constexpr int i1 = PIH(q + 1), j1 = PJH(q + 1); \
  constexpr int i2 = PIH(q + 2), j2 = PJH(q + 2); \
  constexpr int i3 = PIH(q + 3), j3 = PJH(q + 3); \
  float xx0 = xr[i0] * xr[j0], xx1 = xr[i1] * xr[j1]; \
  float xx2 = xr[i2] * xr[j2], xx3 = xr[i3] * xr[j3]; \
  float xxE = selG1 ? xx1 : xx0; \
  float xxO = selG1 ? xx3 : xx2; \
  float xx = selOdd ? xxO : xxE; \
  PACK_MFMA(xx * xr[8], xx * xr[9], xx * xr[10], xx * xr[11], \
            xx * xr[12], xx * xr[13], xx * xr[14], xx * xr[15], KK, ACC) \
}

#define TAIL_STEP(KK, ACC) { \
  float mv[8]; \
  _Pragma("unroll") \
  for (int jj = 0; jj < 8; ++jj) { \
    int spec = sTw[((KK) - 43) * 32 + g * 8 + jj]; \
    mv[jj] = sXw[spec & 31] * sXw[(spec >> 8) & 31]; \
  } \
  PACK_MFMA(mv[0], mv[1], mv[2], mv[3], mv[4], mv[5], mv[6], mv[7], KK, ACC) \
}

__global__ __launch_bounds__(256, 4) void k_main(const float* __restrict__ x,
                                                 const int* __restrict__ offs,
                                                 const int* __restrict__ list,
                                                 const unsigned short* __restrict__ W,
                                                 float* __restrict__ out) {
  __shared__ float sX[4][16][18];
  __shared__ int sT[4][160];
  int t = threadIdx.x;
  int w = t >> 6, lane = t & 63;
  int rc = lane & 15;
  int g = lane >> 4;
  bool selOdd = g >= 2;
  bool selG1 = g & 1;

  int u = blockIdx.x;
  int ec = (u >> 4) * 8 + (u & 7);     // blocks u and u+8 share ec, same XCD (u%8)
  int half = (u >> 3) & 1;
  int e = ec >> 6, c = ec & 63;

  float* sXw = &sX[w][rc][0];
  int* sTw = &sT[w][0];
  for (int r = lane; r < 160; r += 64) {   // per-wave spec fill: no barrier needed
    int a, b;
    if (r < 136) { int p = r, i2 = 0; while (p >= 16 - i2) { p -= 16 - i2; ++i2; } a = i2; b = i2 + p; }
    else if (r < 152) { a = r - 136; b = 16; }
    else { a = 17; b = 17; }
    sTw[r] = a | (b << 8);
  }

  int off = offs[e], nb = offs[e + 1] - off;
  int nt = (nb + 15) >> 4;
  const unsigned short* bp = W + (((size_t)ec * 16 + rc) * NCHUNK + g) * 8;

  for (int tile = half * 4 + w; tile < nt; tile += 8) {
    int m = tile * 16 + rc;
    int node = list[off + (m < nb ? m : nb - 1)];
    float xr[16];
    {
      const float4* xp = (const float4*)(x + ((size_t)node * NCH + c) * 16);
      float4 q0 = xp[0], q1 = xp[1], q2 = xp[2], q3 = xp[3];
      xr[0] = q0.x; xr[1] = q0.y; xr[2] = q0.z; xr[3] = q0.w;
      xr[4] = q1.x; xr[5] = q1.y; xr[6] = q1.z; xr[7] = q1.w;
      xr[8] = q2.x; xr[9] = q2.y; xr[10] = q2.z; xr[11] = q2.w;
      xr[12] = q3.x; xr[13] = q3.y; xr[14] = q3.z; xr[15] = q3.w;
    }
    float xsF[8];
#pragma unroll
    for (int j = 0; j < 8; ++j) xsF[j] = selG1 ? xr[8 + j] : xr[j];
    if (g == 0) {                      // publish row for tail steps (same-wave use only)
#pragma unroll
      for (int l = 0; l < 16; ++l) sXw[l] = xr[l];
      sXw[16] = 1.f; sXw[17] = 0.f;
    }

    float4v acc0 = {0.f, 0.f, 0.f, 0.f};
    float4v acc1 = {0.f, 0.f, 0.f, 0.f};
#define S2F(K) FULL_STEP(K, acc0) FULL_STEP((K) + 1, acc1)
#define S2H(K) H1_STEP(K, acc0) H1_STEP((K) + 1, acc1)
    S2F(0) S2F(2) S2F(4) S2F(6) S2F(8) S2F(10) S2F(12) S2F(14) S2F(16)
    S2H(18) S2H(20) S2H(22) S2H(24) S2H(26) S2H(28) S2H(30) S2H(32)
    S2H(34) S2H(36) S2H(38) S2H(40)
    H1_STEP(42, acc0)
    TAIL_STEP(43, acc1)
    TAIL_STEP(44, acc0) TAIL_STEP(45, acc1)
    TAIL_STEP(46, acc0) TAIL_STEP(47, acc1)
    float4v accs = acc0 + acc1;

#pragma unroll
    for (int r2 = 0; r2 < 4; ++r2) {
      int row = g * 4 + r2;
      int mrow = tile * 16 + row;
      if (mrow < nb) {
        int nd = __shfl(node, row);
        out[((size_t)nd * NCH + c) * 16 + rc] = accs[r2];
      }
    }
  }
}

extern "C" void kernel_launch(void* const* d_in, const int* in_sizes, int n_in,
                              void* d_out, int out_size, void* d_ws, size_t ws_size,
                              hipStream_t stream) {
  (void)in_sizes; (void)n_in; (void)out_size; (void)ws_size;
  const float* x   = (const float*)d_in[0];
  const int*   idx = (const int*)d_in[1];
  const float* w1  = (const float*)d_in[2];
  const float* w2  = (const float*)d_in[3];
  const float* w3  = (const float*)d_in[4];
  const float* U1  = (const float*)d_in[5];
  const float* U2  = (const float*)d_in[6];
  const float* U3  = (const float*)d_in[7];
  float* out = (float*)d_out;
  char* ws = (char*)d_ws;
  int* ws_offs = (int*)(ws + WS_OFFS);
  int* ws_list = (int*)(ws + WS_LIST);
  unsigned short* W = (unsigned short*)(ws + WS_W);

  hipLaunchKernelGGL(k_lists, dim3(1), dim3(1024), 0, stream, idx, ws_offs, ws_list);
  hipLaunchKernelGGL(k_build, dim3(1280), dim3(192), 0, stream, U3, U2, U1, w3, w2, w1, W);
  hipLaunchKernelGGL(k_main, dim3(1280), dim3(256), 0, stream, x, ws_offs, ws_list, W, out);
}